// Round 10
// baseline (308.528 us; speedup 1.0000x reference)
//
#include <hip/hip_runtime.h>
#include <hip/hip_bf16.h>
#include <math.h>

typedef unsigned short ushort_t;
typedef short short8 __attribute__((ext_vector_type(8)));
typedef float f32x4 __attribute__((ext_vector_type(4)));

__device__ __forceinline__ float b2f(ushort_t u) {
  union { unsigned u; float f; } v; v.u = ((unsigned)u) << 16; return v.f;
}
__device__ __forceinline__ ushort_t f2b(float f) {
  union { float f; unsigned u; } v; v.f = f;
  unsigned r = (v.u + 0x7FFFu + ((v.u >> 16) & 1u)) >> 16;
  return (ushort_t)r;
}
// fast GELU: tanh form, one exp2 — max abs err ~3e-4
__device__ __forceinline__ float gelu_fast(float v) {
  float u = 0.7978845608f * (v + 0.044715f * v * v * v);
  float a = fabsf(u);
  float t = exp2f(a * -2.8853900817779268f);
  float th = (1.f - t) / (1.f + t);
  th = copysignf(th, u);
  return 0.5f * v * (1.f + th);
}

union U16x8 { uint4 v; ushort_t s[8]; };

typedef const __attribute__((address_space(1))) unsigned int glb_u32;
typedef __attribute__((address_space(3))) unsigned int lds_u32;
__device__ __forceinline__ void gl_lds16(const ushort_t* g, ushort_t* l) {
  __builtin_amdgcn_global_load_lds((glb_u32*)g, (lds_u32*)l, 16, 0, 0);
}

// chunk swizzle for C-tile staging: distinct per quad (bits of row 2-3) and
// spreads readback across all banks (bits of row 0-1); masked to chunk space.
__device__ __forceinline__ int cswz(int row, int nch) {
  return (((row >> 2) & 3) | ((row & 3) << 2)) & (nch - 1);
}

// ---------------- fused f32 -> bf16 convert of all four weight matrices ----------------
__global__ __launch_bounds__(256) void cvt4_kernel(const float* __restrict__ s0,
                                                   const float* __restrict__ s1,
                                                   const float* __restrict__ s2,
                                                   const float* __restrict__ s3,
                                                   ushort_t* __restrict__ d0,
                                                   ushort_t* __restrict__ d1,
                                                   ushort_t* __restrict__ d2,
                                                   ushort_t* __restrict__ d3) {
  long i = (long)blockIdx.x * 256 + threadIdx.x;
  const float* s; ushort_t* d; long off;
  if (i < 196608)       { s = s0; d = d0; off = i; }
  else if (i < 262144)  { s = s1; d = d1; off = i - 196608; }
  else if (i < 524288)  { s = s2; d = d2; off = i - 262144; }
  else                  { s = s3; d = d3; off = i - 524288; }
  float4 f = *(const float4*)(s + off * 4);
  union { uint2 v; ushort_t s[4]; } o;
  o.s[0] = f2b(f.x); o.s[1] = f2b(f.y); o.s[2] = f2b(f.z); o.s[3] = f2b(f.w);
  *(uint2*)(d + off * 4) = o.v;
}

// ---------------- LayerNorm (f32 in, bf16 out) ----------------
__global__ __launch_bounds__(256) void ln_kernel(const float* __restrict__ x,
                                                 const float* __restrict__ w,
                                                 const float* __restrict__ b,
                                                 ushort_t* __restrict__ out) {
  int tid = threadIdx.x, wave = tid >> 6, lane = tid & 63;
  long token = (long)blockIdx.x * 4 + wave;
  const float* xr = x + token * 512 + lane * 8;
  float4 a0 = *(const float4*)xr;
  float4 a1 = *(const float4*)(xr + 4);
  float xf[8] = {a0.x, a0.y, a0.z, a0.w, a1.x, a1.y, a1.z, a1.w};
  float s = 0.f, sq = 0.f;
#pragma unroll
  for (int i = 0; i < 8; i++) { s += xf[i]; sq += xf[i] * xf[i]; }
#pragma unroll
  for (int off = 1; off < 64; off <<= 1) { s += __shfl_xor(s, off); sq += __shfl_xor(sq, off); }
  float m = s * (1.f / 512.f);
  float var = sq * (1.f / 512.f) - m * m;
  float rs = rsqrtf(var + 1e-5f);
  float4 w0 = *(const float4*)(w + lane * 8);
  float4 w1v = *(const float4*)(w + lane * 8 + 4);
  float4 b0 = *(const float4*)(b + lane * 8);
  float4 b1v = *(const float4*)(b + lane * 8 + 4);
  float wf[8] = {w0.x, w0.y, w0.z, w0.w, w1v.x, w1v.y, w1v.z, w1v.w};
  float bf[8] = {b0.x, b0.y, b0.z, b0.w, b1v.x, b1v.y, b1v.z, b1v.w};
  U16x8 o;
#pragma unroll
  for (int i = 0; i < 8; i++) o.s[i] = f2b((xf[i] - m) * rs * wf[i] + bf[i]);
  *(uint4*)(out + token * 512 + lane * 8) = o.v;
}

// ---------------- LayerNorm (bf16 in, bf16 out) ----------------
__global__ __launch_bounds__(256) void ln_b_kernel(const ushort_t* __restrict__ x,
                                                   const float* __restrict__ w,
                                                   const float* __restrict__ b,
                                                   ushort_t* __restrict__ out) {
  int tid = threadIdx.x, wave = tid >> 6, lane = tid & 63;
  long token = (long)blockIdx.x * 4 + wave;
  U16x8 ux; ux.v = *(const uint4*)(x + token * 512 + lane * 8);
  float xf[8], s = 0.f, sq = 0.f;
#pragma unroll
  for (int i = 0; i < 8; i++) { xf[i] = b2f(ux.s[i]); s += xf[i]; sq += xf[i] * xf[i]; }
#pragma unroll
  for (int off = 1; off < 64; off <<= 1) { s += __shfl_xor(s, off); sq += __shfl_xor(sq, off); }
  float m = s * (1.f / 512.f);
  float var = sq * (1.f / 512.f) - m * m;
  float rs = rsqrtf(var + 1e-5f);
  float4 w0 = *(const float4*)(w + lane * 8);
  float4 w1v = *(const float4*)(w + lane * 8 + 4);
  float4 b0 = *(const float4*)(b + lane * 8);
  float4 b1v = *(const float4*)(b + lane * 8 + 4);
  float wf[8] = {w0.x, w0.y, w0.z, w0.w, w1v.x, w1v.y, w1v.z, w1v.w};
  float bf[8] = {b0.x, b0.y, b0.z, b0.w, b1v.x, b1v.y, b1v.z, b1v.w};
  U16x8 o;
#pragma unroll
  for (int i = 0; i < 8; i++) o.s[i] = f2b((xf[i] - m) * rs * wf[i] + bf[i]);
  *(uint4*)(out + token * 512 + lane * 8) = o.v;
}

// ------------- Gaussian position kernel weights -------------
__global__ __launch_bounds__(256) void kw_kernel(const int* __restrict__ posv,
                                                 const int* __restrict__ posh,
                                                 ushort_t* __restrict__ kw) {
  int b = blockIdx.x >> 10, i = blockIdx.x & 1023;
  int tid = threadIdx.x;
  const int* pv = posv + b * 1024;
  const int* ph = posh + b * 1024;
  int pvi = pv[i], phi = ph[i];
  int j0 = tid * 4;
  int4 vj = *(const int4*)(pv + j0);
  int4 hj = *(const int4*)(ph + j0);
  int vv[4] = {vj.x, vj.y, vj.z, vj.w};
  int hh[4] = {hj.x, hj.y, hj.z, hj.w};
  float e[4]; float loc = 0.f;
#pragma unroll
  for (int u = 0; u < 4; u++) {
    int dv = pvi - vv[u], dh = phi - hh[u];
    e[u] = expf((float)(dv * dv + dh * dh) * (-1.f / 512.f));
    loc += e[u];
  }
#pragma unroll
  for (int off = 1; off < 64; off <<= 1) loc += __shfl_xor(loc, off);
  __shared__ float wsum[4];
  __shared__ float tot;
  if ((tid & 63) == 0) wsum[tid >> 6] = loc;
  __syncthreads();
  if (tid == 0) tot = wsum[0] + wsum[1] + wsum[2] + wsum[3];
  __syncthreads();
  float inv = 1.f / tot;
  union { uint2 v; ushort_t s[4]; } o;
#pragma unroll
  for (int u = 0; u < 4; u++) o.s[u] = f2b(e[u] * inv);
  *(uint2*)&kw[((long)(b * 1024 + i)) * 1024 + j0] = o.v;
}

// ---------------- 64x64 tiled transpose ----------------
__global__ __launch_bounds__(256) void tr_kernel(const ushort_t* __restrict__ in,
                                                 ushort_t* __restrict__ out,
                                                 int R, int C) {
  __shared__ ushort_t tile[64 * 64];
  int z = blockIdx.z, r0 = blockIdx.y * 64, c0 = blockIdx.x * 64;
  const ushort_t* src = in + (long)z * R * C;
  ushort_t* dst = out + (long)z * R * C;
  int tid = threadIdx.x;
  int tr = tid >> 2;
  const ushort_t* s = src + (long)(r0 + tr) * C + c0;
  int g = (tr + (tr >> 4)) & 7;
#pragma unroll
  for (int u = 0; u < 2; u++) {
    int c = (tid & 3) + u * 4;
    *(uint4*)&tile[tr * 64 + (c ^ g) * 8] = *(const uint4*)(s + c * 8);
  }
  __syncthreads();
  int oc = tid >> 2, ob = (tid & 3) * 16;
  U16x8 o0, o1;
#pragma unroll
  for (int j = 0; j < 16; j++) {
    int r = ob + j;
    int gg = (r + (r >> 4)) & 7;
    ushort_t val = tile[r * 64 + (((oc >> 3) ^ gg)) * 8 + (oc & 7)];
    if (j < 8) o0.s[j] = val; else o1.s[j - 8] = val;
  }
  ushort_t* d = dst + (long)(c0 + oc) * R + r0 + ob;
  *(uint4*)d = o0.v;
  *(uint4*)(d + 8) = o1.v;
}

// ---------------- dbuf MFMA GEMM + LDS-repacked coalesced epilogue ----------------
struct GemmP {
  const ushort_t* A; const ushort_t* Bm;
  long sA, sB, sC;
  int lda, ldb, ldc, K;
  const float* biasf;
  const float* residf;
  const ushort_t* auxb;
  float* outf;
  ushort_t* outb;
  ushort_t* qp; ushort_t* kp; ushort_t* vp;
  const float* gate;
};

template <int BM, int BN, int EPI>
__global__ __launch_bounds__(256) void gemm_k(GemmP p) {
  constexpr int TI = BM / 32, TJ = BN / 32;
  constexpr int RA = BM / 64, RB = BN / 64;
  constexpr int STAGE = (BM + BN) * 128;                    // bytes: dbuf bf16 K=32
  constexpr int CB = (EPI == 4) ? BM * BN * 4 : BM * BN * 2;
  constexpr int SB = (STAGE > CB) ? STAGE : CB;
  __shared__ __align__(16) char smem[SB];
  ushort_t* AsB = (ushort_t*)smem;                          // [2][BM*32]
  ushort_t* BsB = (ushort_t*)(smem + (size_t)BM * 128);     // [2][BN*32]

  int tid = threadIdx.x, wv = tid >> 6, lane = tid & 63;
  int quad = lane >> 4, l15 = lane & 15;
  int bl = blockIdx.x + gridDim.x * blockIdx.y;
  int m0 = (bl % gridDim.y) * BM;
  int n0 = (bl / gridDim.y) * BN;
  int z = blockIdx.z;
  const ushort_t* A = p.A + (long)z * p.sA;
  const ushort_t* Bm = p.Bm + (long)z * p.sB;
  int wm = (wv & 1) * (BM / 2), wn = (wv >> 1) * (BN / 2);
  f32x4 acc[TI][TJ];
#pragma unroll
  for (int i = 0; i < TI; i++)
#pragma unroll
    for (int j = 0; j < TJ; j++)
#pragma unroll
      for (int r = 0; r < 4; r++) acc[i][j][r] = 0.f;

  int srow = tid >> 2;
  int sc = ((tid & 3) ^ ((tid >> 3) & 3)) * 8;
  const ushort_t* ga = A + (long)(m0 + srow) * p.lda + sc;
  const ushort_t* gb = Bm + (long)(n0 + srow) * p.ldb + sc;
  long a64 = (long)64 * p.lda, b64 = (long)64 * p.ldb;
  int aswz = (quad ^ ((l15 >> 1) & 3)) * 8;
  int nsteps = p.K >> 5;

#pragma unroll
  for (int rr = 0; rr < RA; rr++)
    gl_lds16(ga + rr * a64, AsB + rr * 2048 + wv * 512);
#pragma unroll
  for (int rr = 0; rr < RB; rr++)
    gl_lds16(gb + rr * b64, BsB + rr * 2048 + wv * 512);
  __syncthreads();

  for (int ks = 0; ks < nsteps; ks++) {
    int cur = ks & 1;
    ushort_t* Asc = AsB + cur * BM * 32;
    ushort_t* Bsc = BsB + cur * BN * 32;
    if (ks + 1 < nsteps) {
      ushort_t* Asn = AsB + (cur ^ 1) * BM * 32;
      ushort_t* Bsn = BsB + (cur ^ 1) * BN * 32;
      const ushort_t* a0 = ga + (ks + 1) * 32;
      const ushort_t* b0 = gb + (ks + 1) * 32;
#pragma unroll
      for (int rr = 0; rr < RA; rr++)
        gl_lds16(a0 + rr * a64, Asn + rr * 2048 + wv * 512);
#pragma unroll
      for (int rr = 0; rr < RB; rr++)
        gl_lds16(b0 + rr * b64, Bsn + rr * 2048 + wv * 512);
    }
    short8 av[TI], bv[TJ];
#pragma unroll
    for (int ti = 0; ti < TI; ti++)
      av[ti] = *(const short8*)&Asc[(wm + ti * 16 + l15) * 32 + aswz];
#pragma unroll
    for (int tj = 0; tj < TJ; tj++)
      bv[tj] = *(const short8*)&Bsc[(wn + tj * 16 + l15) * 32 + aswz];
#pragma unroll
    for (int ti = 0; ti < TI; ti++)
#pragma unroll
      for (int tj = 0; tj < TJ; tj++)
        acc[ti][tj] = __builtin_amdgcn_mfma_f32_16x16x32_bf16(av[ti], bv[tj], acc[ti][tj], 0, 0, 0);
    __syncthreads();
  }

  // ---- stage C tile into LDS (swizzled), then coalesced writeout ----
  float g = 0.f;
  if constexpr (EPI == 2) g = 1.f / (1.f + expf(-p.gate[0]));
  constexpr int NCH = BN / 8;  // bf16 16B chunks per row
  if constexpr (EPI != 4) {
    ushort_t* C = (ushort_t*)smem;
#pragma unroll
    for (int ti = 0; ti < TI; ti++)
#pragma unroll
      for (int tj = 0; tj < TJ; tj++)
#pragma unroll
        for (int r = 0; r < 4; r++) {
          int row = wm + ti * 16 + quad * 4 + r;
          int col = wn + tj * 16 + l15;
          float v = acc[ti][tj][r];
          if constexpr (EPI == 0) {
            int n = n0 + col;
            v += p.biasf[n];
            if (n < 512) v *= 0.18033688011112042f;  // q pre-scale for exp2 softmax
          } else if constexpr (EPI == 2) {
            v += p.biasf[n0 + col];
          } else if constexpr (EPI == 3) {
            v = gelu_fast(v + p.biasf[n0 + col]);
          }
          int ch = (col >> 3) ^ cswz(row, NCH);
          C[row * BN + ch * 8 + (col & 7)] = f2b(v);
        }
  } else {
    float* C = (float*)smem;
    constexpr int NCF = BN / 4;
#pragma unroll
    for (int ti = 0; ti < TI; ti++)
#pragma unroll
      for (int tj = 0; tj < TJ; tj++)
#pragma unroll
        for (int r = 0; r < 4; r++) {
          int row = wm + ti * 16 + quad * 4 + r;
          int col = wn + tj * 16 + l15;
          float v = acc[ti][tj][r] + p.biasf[n0 + col];
          int ch = (col >> 2) ^ cswz(row, NCF);
          C[row * BN + ch * 4 + (col & 3)] = v;
        }
  }
  __syncthreads();

  if constexpr (EPI == 0) {
    // q/k/v split: row=token, 64-col run = one head slice (contiguous 128 B)
    ushort_t* C = (ushort_t*)smem;
    int row = tid >> 1, half = tid & 1;
    int gm = m0 + row, bb = gm >> 10, tt = gm & 1023;
    int n = n0 + half * 64;
    ushort_t* dst;
    if (n < 512)        dst = p.qp + ((long)(bb * 8 + (n >> 6)) * 1024 + tt) * 64;
    else if (n < 1024)  dst = p.kp + ((long)(bb * 8 + ((n - 512) >> 6)) * 1024 + tt) * 64;
    else                dst = p.vp + ((long)(bb * 8 + ((n - 1024) >> 6)) * 1024 + tt) * 64;
    int sw = cswz(row, NCH);
#pragma unroll
    for (int c = 0; c < 8; c++) {
      int ch = (half * 8 + c) ^ sw;
      *(uint4*)(dst + c * 8) = *(const uint4*)&C[row * BN + ch * 8];
    }
  } else if constexpr (EPI == 1) {
    ushort_t* C = (ushort_t*)smem;
    int row = tid >> 2, qq = tid & 3;   // BM=64, BN=128: 32 cols/thread
    long base = (long)z * p.sC + (long)(m0 + row) * p.ldc + n0 + qq * 32;
    int sw = cswz(row, NCH);
#pragma unroll
    for (int c = 0; c < 4; c++) {
      int ch = (qq * 4 + c) ^ sw;
      *(uint4*)(p.outb + base + c * 8) = *(const uint4*)&C[row * BN + ch * 8];
    }
  } else if constexpr (EPI == 2) {
    ushort_t* C = (ushort_t*)smem;
    int row = tid >> 2, qq = tid & 3;   // BM=64, BN=64: 16 cols/thread
    long idx = (long)(m0 + row) * 512 + n0 + qq * 16;
    int sw = cswz(row, NCH);
    float rv[16];
#pragma unroll
    for (int u = 0; u < 4; u++)
      *(float4*)&rv[u * 4] = *(const float4*)(p.residf + idx + u * 4);
    U16x8 a0, a1;
    a0.v = *(const uint4*)(p.auxb + idx);
    a1.v = *(const uint4*)(p.auxb + idx + 8);
    U16x8 c0, c1;
    c0.v = *(const uint4*)&C[row * BN + ((qq * 2) ^ sw) * 8];
    c1.v = *(const uint4*)&C[row * BN + ((qq * 2 + 1) ^ sw) * 8];
    U16x8 o0, o1;
#pragma unroll
    for (int i = 0; i < 8; i++) {
      o0.s[i] = f2b(rv[i] + g * b2f(c0.s[i]) + (1.f - g) * b2f(a0.s[i]));
      o1.s[i] = f2b(rv[8 + i] + g * b2f(c1.s[i]) + (1.f - g) * b2f(a1.s[i]));
    }
    *(uint4*)(p.outb + idx) = o0.v;
    *(uint4*)(p.outb + idx + 8) = o1.v;
  } else if constexpr (EPI == 3) {
    ushort_t* C = (ushort_t*)smem;
    int row = tid >> 1, half = tid & 1;  // BM=128, BN=128
    long base = (long)(m0 + row) * p.ldc + n0 + half * 64;
    int sw = cswz(row, NCH);
#pragma unroll
    for (int c = 0; c < 8; c++) {
      int ch = (half * 8 + c) ^ sw;
      *(uint4*)(p.outb + base + c * 8) = *(const uint4*)&C[row * BN + ch * 8];
    }
  } else {  // EPI == 4: f32 out + bf16 residual add
    float* C = (float*)smem;
    constexpr int NCF = BN / 4;
    int row = tid >> 2, qq = tid & 3;   // BM=64, BN=128: 32 cols/thread
    long idx = (long)(m0 + row) * 512 + n0 + qq * 32;
    int sw = cswz(row, NCF);
#pragma unroll
    for (int c = 0; c < 8; c++) {
      int ch = (qq * 8 + c) ^ sw;
      float4 cv = *(const float4*)&C[row * BN + ch * 4];
      union { uint2 u; ushort_t s[4]; } ax;
      ax.u = *(const uint2*)(p.auxb + idx + c * 4);
      float4 ov;
      ov.x = cv.x + b2f(ax.s[0]); ov.y = cv.y + b2f(ax.s[1]);
      ov.z = cv.z + b2f(ax.s[2]); ov.w = cv.w + b2f(ax.s[3]);
      *(float4*)(p.outf + idx + c * 4) = ov;
    }
  }
}

// ---------------- Flash attention v2: S^T form, packed P writes, Q in regs ----------------
__global__ __launch_bounds__(256) void flash_k(const ushort_t* __restrict__ q,
                                               const ushort_t* __restrict__ k,
                                               const ushort_t* __restrict__ vT,
                                               ushort_t* __restrict__ ctx) {
  int bl = blockIdx.x + gridDim.x * blockIdx.y;
  int bh = bl % 64;
  int q0 = (bl / 64) * 128;
  int tid = threadIdx.x, wv = tid >> 6, lane = tid & 63;
  int quad = lane >> 4, l15 = lane & 15;
  __shared__ ushort_t Ks[2][64 * 64], Vt[2][64 * 64];
  __shared__ ushort_t Pt[128 * 64];
  int wm = wv * 32;

  short8 qf[2][2];
#pragma unroll
  for (int tq = 0; tq < 2; tq++)
#pragma unroll
    for (int kk = 0; kk < 2; kk++)
      qf[tq][kk] = *(const short8*)&q[((long)bh * 1024 + q0 + wm + tq * 16 + l15) * 64 + kk * 32 + quad * 8];

  int srow = tid >> 3;
  int sc = ((tid & 7) ^ ((tid >> 3) & 7)) * 8;
#pragma unroll
  for (int e = 0; e < 2; e++) {
    gl_lds16(&k[((long)bh * 1024 + e * 32 + srow) * 64 + sc], Ks[0] + e * 2048 + wv * 512);
    gl_lds16(&vT[((long)bh * 64 + e * 32 + srow) * 1024 + sc], Vt[0] + e * 2048 + wv * 512);
  }
  __syncthreads();

  f32x4 O[2][4];
#pragma unroll
  for (int tq = 0; tq < 2; tq++)
#pragma unroll
    for (int td = 0; td < 4; td++)
#pragma unroll
      for (int r = 0; r < 4; r++) O[tq][td][r] = 0.f;
  float ls[2] = {0.f, 0.f};

  int pswz = (l15 & 7) << 1;
  for (int kt = 0; kt < 16; kt++) {
    int cur = kt & 1;
    if (kt + 1 < 16) {
#pragma unroll
      for (int e = 0; e < 2; e++) {
        gl_lds16(&k[((long)bh * 1024 + (kt + 1) * 64 + e * 32 + srow) * 64 + sc], Ks[cur ^ 1] + e * 2048 + wv * 512);
        gl_lds16(&vT[((long)bh * 64 + e * 32 + srow) * 1024 + (kt + 1) * 64 + sc], Vt[cur ^ 1] + e * 2048 + wv * 512);
      }
    }
#pragma unroll
    for (int tq = 0; tq < 2; tq++) {
      f32x4 S[4];
#pragma unroll
      for (int tk = 0; tk < 4; tk++) {
#pragma unroll
        for (int r = 0; r < 4; r++) S[tk][r] = 0.f;
#pragma unroll
        for (int kk = 0; kk < 2; kk++) {
          short8 kf = *(const short8*)&Ks[cur][(tk * 16 + l15) * 64 + ((kk * 4 + quad) ^ (l15 & 7)) * 8];
          S[tk] = __builtin_amdgcn_mfma_f32_16x16x32_bf16(kf, qf[tq][kk], S[tk], 0, 0, 0);
        }
      }
#pragma unroll
      for (int tk = 0; tk < 4; tk++) {
        float p0 = exp2f(S[tk][0]);
        float p1 = exp2f(S[tk][1]);
        float p2 = exp2f(S[tk][2]);
        float p3 = exp2f(S[tk][3]);
        ls[tq] += (p0 + p1) + (p2 + p3);
        unsigned lo = __builtin_amdgcn_perm(__float_as_uint(p1), __float_as_uint(p0), 0x07060302u);
        unsigned hi = __builtin_amdgcn_perm(__float_as_uint(p3), __float_as_uint(p2), 0x07060302u);
        int gnum = (tk * 4 + quad) ^ pswz;
        uint2 pr; pr.x = lo; pr.y = hi;
        *(uint2*)&Pt[(wm + tq * 16 + l15) * 64 + gnum * 4] = pr;
      }
    }
#pragma unroll
    for (int tq = 0; tq < 2; tq++) {
#pragma unroll
      for (int kk = 0; kk < 2; kk++) {
        short8 pf = *(const short8*)&Pt[(wm + tq * 16 + l15) * 64 + (((kk * 8 + quad * 2) ^ pswz)) * 4];
#pragma unroll
        for (int td = 0; td < 4; td++) {
          short8 vf = *(const short8*)&Vt[cur][(td * 16 + l15) * 64 + ((kk * 4 + quad) ^ (l15 & 7)) * 8];
          O[tq][td] = __builtin_amdgcn_mfma_f32_16x16x32_bf16(pf, vf, O[tq][td], 0, 0, 0);
        }
      }
    }
    __syncthreads();
  }
#pragma unroll
  for (int tq = 0; tq < 2; tq++) {
    ls[tq] += __shfl_xor(ls[tq], 16);
    ls[tq] += __shfl_xor(ls[tq], 32);
  }
  int bb = bh >> 3, h = bh & 7;
#pragma unroll
  for (int tq = 0; tq < 2; tq++) {
#pragma unroll
    for (int r = 0; r < 4; r++) {
      int qrow = quad * 4 + r;
      float inv = 1.f / __shfl(ls[tq], (lane & 48) | qrow);
      long row = (long)bb * 1024 + q0 + wm + tq * 16 + qrow;
#pragma unroll
      for (int td = 0; td < 4; td++)
        ctx[row * 512 + h * 64 + td * 16 + l15] = f2b(O[tq][td][r] * inv);
    }
  }
}

// ---------------- launch ----------------
extern "C" void kernel_launch(void* const* d_in, const int* in_sizes, int n_in,
                              void* d_out, int out_size, void* d_ws, size_t ws_size,
                              hipStream_t stream) {
  const float* x    = (const float*)d_in[0];
  const int* posv   = (const int*)d_in[1];
  const int* posh   = (const int*)d_in[2];
  const float* n1w  = (const float*)d_in[3];
  const float* n1b  = (const float*)d_in[4];
  const float* in_w = (const float*)d_in[5];
  const float* in_b = (const float*)d_in[6];
  const float* outw = (const float*)d_in[7];
  const float* outb = (const float*)d_in[8];
  const float* n2w  = (const float*)d_in[9];
  const float* n2b  = (const float*)d_in[10];
  const float* w1   = (const float*)d_in[11];
  const float* b1   = (const float*)d_in[12];
  const float* w2   = (const float*)d_in[13];
  const float* b2   = (const float*)d_in[14];
  const float* gate = (const float*)d_in[15];
  float* out = (float*)d_out;

  char* ws = (char*)d_ws;
  const size_t MB = 1024 * 1024;
  ushort_t* q    = (ushort_t*)(ws + 0 * MB);
  ushort_t* kk   = (ushort_t*)(ws + 8 * MB);
  ushort_t* vtmp = (ushort_t*)(ws + 16 * MB);
  ushort_t* vT   = (ushort_t*)(ws + 24 * MB);
  ushort_t* kw   = (ushort_t*)(ws + 32 * MB);
  ushort_t* xn   = (ushort_t*)(ws + 48 * MB);
  ushort_t* xnT  = (ushort_t*)(ws + 56 * MB);
  ushort_t* ctx  = (ushort_t*)(ws + 64 * MB);
  ushort_t* ko   = (ushort_t*)(ws + 72 * MB);
  ushort_t* x1b  = (ushort_t*)(ws + 80 * MB);
  ushort_t* xn2  = (ushort_t*)(ws + 16 * MB);   // overlay vtmp
  ushort_t* inwb = (ushort_t*)(ws + 96 * MB);
  ushort_t* owb  = (ushort_t*)(ws + 98 * MB);
  ushort_t* w1b  = (ushort_t*)(ws + 99 * MB);
  ushort_t* w2b  = (ushort_t*)(ws + 101 * MB);
  ushort_t* h    = (ushort_t*)(ws + 24 * MB);   // 32 MB overlay (vT/kw/xn dead)

  cvt4_kernel<<<3072, 256, 0, stream>>>(in_w, outw, w1, w2, inwb, owb, w1b, w2b);
  ln_kernel<<<2048, 256, 0, stream>>>(x, n1w, n1b, xn);
  kw_kernel<<<8192, 256, 0, stream>>>(posv, posh, kw);
  // qkv: [8192,1536] = xn @ in_w^T
  {
    GemmP p = {};
    p.A = xn; p.Bm = inwb; p.lda = 512; p.ldb = 512; p.K = 512;
    p.biasf = in_b; p.qp = q; p.kp = kk; p.vp = vtmp;
    gemm_k<128, 128, 0><<<dim3(12, 64, 1), 256, 0, stream>>>(p);
  }
  tr_kernel<<<dim3(1, 16, 64), 256, 0, stream>>>(vtmp, vT, 1024, 64);
  flash_k<<<dim3(8, 64, 1), 256, 0, stream>>>(q, kk, vT, ctx);
  tr_kernel<<<dim3(8, 16, 8), 256, 0, stream>>>(xn, xnT, 1024, 512);
  // kernel_out = kw @ xn (batched) -> ko bf16
  {
    GemmP p = {};
    p.A = kw; p.Bm = xnT; p.lda = 1024; p.ldb = 1024; p.ldc = 512; p.K = 1024;
    p.sA = 1024L * 1024; p.sB = 512L * 1024; p.sC = 1024L * 512;
    p.outb = ko;
    gemm_k<64, 128, 1><<<dim3(4, 16, 8), 256, 0, stream>>>(p);
  }
  // std_out + gate combine -> x1 bf16
  {
    GemmP p = {};
    p.A = ctx; p.Bm = owb; p.lda = 512; p.ldb = 512; p.K = 512;
    p.biasf = outb; p.residf = x; p.auxb = ko; p.outb = x1b; p.gate = gate;
    gemm_k<64, 64, 2><<<dim3(8, 128, 1), 256, 0, stream>>>(p);
  }
  ln_b_kernel<<<2048, 256, 0, stream>>>(x1b, n2w, n2b, xn2);
  // MLP1 + GELU -> h bf16
  {
    GemmP p = {};
    p.A = xn2; p.Bm = w1b; p.lda = 512; p.ldb = 512; p.ldc = 2048; p.K = 512;
    p.biasf = b1; p.outb = h;
    gemm_k<128, 128, 3><<<dim3(16, 64, 1), 256, 0, stream>>>(p);
  }
  // MLP2 + residual(x1b) -> out f32
  {
    GemmP p = {};
    p.A = h; p.Bm = w2b; p.lda = 2048; p.ldb = 2048; p.K = 2048;
    p.biasf = b2; p.auxb = x1b; p.outf = out;
    gemm_k<64, 128, 4><<<dim3(4, 128, 1), 256, 0, stream>>>(p);
  }
}

// Round 11
// 301.244 us; speedup vs baseline: 1.0242x; 1.0242x over previous
//
#include <hip/hip_runtime.h>
#include <hip/hip_bf16.h>
#include <math.h>

typedef unsigned short ushort_t;
typedef short short8 __attribute__((ext_vector_type(8)));
typedef float f32x4 __attribute__((ext_vector_type(4)));

__device__ __forceinline__ float b2f(ushort_t u) {
  union { unsigned u; float f; } v; v.u = ((unsigned)u) << 16; return v.f;
}
__device__ __forceinline__ ushort_t f2b(float f) {
  union { float f; unsigned u; } v; v.f = f;
  unsigned r = (v.u + 0x7FFFu + ((v.u >> 16) & 1u)) >> 16;
  return (ushort_t)r;
}
// fast GELU: tanh form, one exp2 — max abs err ~3e-4
__device__ __forceinline__ float gelu_fast(float v) {
  float u = 0.7978845608f * (v + 0.044715f * v * v * v);
  float a = fabsf(u);
  float t = exp2f(a * -2.8853900817779268f);
  float th = (1.f - t) / (1.f + t);
  th = copysignf(th, u);
  return 0.5f * v * (1.f + th);
}

union U16x8 { uint4 v; ushort_t s[8]; };

typedef const __attribute__((address_space(1))) unsigned int glb_u32;
typedef __attribute__((address_space(3))) unsigned int lds_u32;
__device__ __forceinline__ void gl_lds16(const ushort_t* g, ushort_t* l) {
  __builtin_amdgcn_global_load_lds((glb_u32*)g, (lds_u32*)l, 16, 0, 0);
}

// ---------------- fused f32 -> bf16 convert of all four weight matrices ----------------
__global__ __launch_bounds__(256) void cvt4_kernel(const float* __restrict__ s0,
                                                   const float* __restrict__ s1,
                                                   const float* __restrict__ s2,
                                                   const float* __restrict__ s3,
                                                   ushort_t* __restrict__ d0,
                                                   ushort_t* __restrict__ d1,
                                                   ushort_t* __restrict__ d2,
                                                   ushort_t* __restrict__ d3) {
  long i = (long)blockIdx.x * 256 + threadIdx.x;
  const float* s; ushort_t* d; long off;
  if (i < 196608)       { s = s0; d = d0; off = i; }
  else if (i < 262144)  { s = s1; d = d1; off = i - 196608; }
  else if (i < 524288)  { s = s2; d = d2; off = i - 262144; }
  else                  { s = s3; d = d3; off = i - 524288; }
  float4 f = *(const float4*)(s + off * 4);
  union { uint2 v; ushort_t s[4]; } o;
  o.s[0] = f2b(f.x); o.s[1] = f2b(f.y); o.s[2] = f2b(f.z); o.s[3] = f2b(f.w);
  *(uint2*)(d + off * 4) = o.v;
}

// ---------------- LayerNorm (f32 in, bf16 out) ----------------
__global__ __launch_bounds__(256) void ln_kernel(const float* __restrict__ x,
                                                 const float* __restrict__ w,
                                                 const float* __restrict__ b,
                                                 ushort_t* __restrict__ out) {
  int tid = threadIdx.x, wave = tid >> 6, lane = tid & 63;
  long token = (long)blockIdx.x * 4 + wave;
  const float* xr = x + token * 512 + lane * 8;
  float4 a0 = *(const float4*)xr;
  float4 a1 = *(const float4*)(xr + 4);
  float xf[8] = {a0.x, a0.y, a0.z, a0.w, a1.x, a1.y, a1.z, a1.w};
  float s = 0.f, sq = 0.f;
#pragma unroll
  for (int i = 0; i < 8; i++) { s += xf[i]; sq += xf[i] * xf[i]; }
#pragma unroll
  for (int off = 1; off < 64; off <<= 1) { s += __shfl_xor(s, off); sq += __shfl_xor(sq, off); }
  float m = s * (1.f / 512.f);
  float var = sq * (1.f / 512.f) - m * m;
  float rs = rsqrtf(var + 1e-5f);
  float4 w0 = *(const float4*)(w + lane * 8);
  float4 w1v = *(const float4*)(w + lane * 8 + 4);
  float4 b0 = *(const float4*)(b + lane * 8);
  float4 b1v = *(const float4*)(b + lane * 8 + 4);
  float wf[8] = {w0.x, w0.y, w0.z, w0.w, w1v.x, w1v.y, w1v.z, w1v.w};
  float bf[8] = {b0.x, b0.y, b0.z, b0.w, b1v.x, b1v.y, b1v.z, b1v.w};
  U16x8 o;
#pragma unroll
  for (int i = 0; i < 8; i++) o.s[i] = f2b((xf[i] - m) * rs * wf[i] + bf[i]);
  *(uint4*)(out + token * 512 + lane * 8) = o.v;
}

// ---------------- LayerNorm (bf16 in, bf16 out) ----------------
__global__ __launch_bounds__(256) void ln_b_kernel(const ushort_t* __restrict__ x,
                                                   const float* __restrict__ w,
                                                   const float* __restrict__ b,
                                                   ushort_t* __restrict__ out) {
  int tid = threadIdx.x, wave = tid >> 6, lane = tid & 63;
  long token = (long)blockIdx.x * 4 + wave;
  U16x8 ux; ux.v = *(const uint4*)(x + token * 512 + lane * 8);
  float xf[8], s = 0.f, sq = 0.f;
#pragma unroll
  for (int i = 0; i < 8; i++) { xf[i] = b2f(ux.s[i]); s += xf[i]; sq += xf[i] * xf[i]; }
#pragma unroll
  for (int off = 1; off < 64; off <<= 1) { s += __shfl_xor(s, off); sq += __shfl_xor(sq, off); }
  float m = s * (1.f / 512.f);
  float var = sq * (1.f / 512.f) - m * m;
  float rs = rsqrtf(var + 1e-5f);
  float4 w0 = *(const float4*)(w + lane * 8);
  float4 w1v = *(const float4*)(w + lane * 8 + 4);
  float4 b0 = *(const float4*)(b + lane * 8);
  float4 b1v = *(const float4*)(b + lane * 8 + 4);
  float wf[8] = {w0.x, w0.y, w0.z, w0.w, w1v.x, w1v.y, w1v.z, w1v.w};
  float bf[8] = {b0.x, b0.y, b0.z, b0.w, b1v.x, b1v.y, b1v.z, b1v.w};
  U16x8 o;
#pragma unroll
  for (int i = 0; i < 8; i++) o.s[i] = f2b((xf[i] - m) * rs * wf[i] + bf[i]);
  *(uint4*)(out + token * 512 + lane * 8) = o.v;
}

// ------------- Gaussian position kernel weights -------------
__global__ __launch_bounds__(256) void kw_kernel(const int* __restrict__ posv,
                                                 const int* __restrict__ posh,
                                                 ushort_t* __restrict__ kw) {
  int b = blockIdx.x >> 10, i = blockIdx.x & 1023;
  int tid = threadIdx.x;
  const int* pv = posv + b * 1024;
  const int* ph = posh + b * 1024;
  int pvi = pv[i], phi = ph[i];
  int j0 = tid * 4;
  int4 vj = *(const int4*)(pv + j0);
  int4 hj = *(const int4*)(ph + j0);
  int vv[4] = {vj.x, vj.y, vj.z, vj.w};
  int hh[4] = {hj.x, hj.y, hj.z, hj.w};
  float e[4]; float loc = 0.f;
#pragma unroll
  for (int u = 0; u < 4; u++) {
    int dv = pvi - vv[u], dh = phi - hh[u];
    e[u] = expf((float)(dv * dv + dh * dh) * (-1.f / 512.f));
    loc += e[u];
  }
#pragma unroll
  for (int off = 1; off < 64; off <<= 1) loc += __shfl_xor(loc, off);
  __shared__ float wsum[4];
  __shared__ float tot;
  if ((tid & 63) == 0) wsum[tid >> 6] = loc;
  __syncthreads();
  if (tid == 0) tot = wsum[0] + wsum[1] + wsum[2] + wsum[3];
  __syncthreads();
  float inv = 1.f / tot;
  union { uint2 v; ushort_t s[4]; } o;
#pragma unroll
  for (int u = 0; u < 4; u++) o.s[u] = f2b(e[u] * inv);
  *(uint2*)&kw[((long)(b * 1024 + i)) * 1024 + j0] = o.v;
}

// ---------------- 64x64 tiled transpose ----------------
__global__ __launch_bounds__(256) void tr_kernel(const ushort_t* __restrict__ in,
                                                 ushort_t* __restrict__ out,
                                                 int R, int C) {
  __shared__ ushort_t tile[64 * 64];
  int z = blockIdx.z, r0 = blockIdx.y * 64, c0 = blockIdx.x * 64;
  const ushort_t* src = in + (long)z * R * C;
  ushort_t* dst = out + (long)z * R * C;
  int tid = threadIdx.x;
  int tr = tid >> 2;
  const ushort_t* s = src + (long)(r0 + tr) * C + c0;
  int g = (tr + (tr >> 4)) & 7;
#pragma unroll
  for (int u = 0; u < 2; u++) {
    int c = (tid & 3) + u * 4;
    *(uint4*)&tile[tr * 64 + (c ^ g) * 8] = *(const uint4*)(s + c * 8);
  }
  __syncthreads();
  int oc = tid >> 2, ob = (tid & 3) * 16;
  U16x8 o0, o1;
#pragma unroll
  for (int j = 0; j < 16; j++) {
    int r = ob + j;
    int gg = (r + (r >> 4)) & 7;
    ushort_t val = tile[r * 64 + (((oc >> 3) ^ gg)) * 8 + (oc & 7)];
    if (j < 8) o0.s[j] = val; else o1.s[j - 8] = val;
  }
  ushort_t* d = dst + (long)(c0 + oc) * R + r0 + ob;
  *(uint4*)d = o0.v;
  *(uint4*)(d + 8) = o1.v;
}

// ---- 3-stage async-pipelined MFMA GEMM: raw s_barrier + manual vmcnt (no drain) ----
// Prefetch runs 2 tiles ahead; each iter waits only its own tile's NV loads.
// WAR on the 3 rotating buffers is protected by the single barrier per iter.
struct GemmP {
  const ushort_t* A; const ushort_t* Bm;
  long sA, sB, sC;
  int lda, ldb, ldc, K;
  const float* biasf;
  const float* residf;
  const ushort_t* auxb;
  float* outf;
  ushort_t* outb;
  ushort_t* qp; ushort_t* kp; ushort_t* vp;
  const float* gate;
};

template <int BM, int BN, int EPI>
__global__ __launch_bounds__(256) void gemm_k(GemmP p) {
  constexpr int TI = BM / 32, TJ = BN / 32;
  constexpr int RA = BM / 64, RB = BN / 64;
  constexpr int NV = RA + RB;      // DMA instructions per wave per tile
  __shared__ ushort_t As[3][BM * 32];
  __shared__ ushort_t Bs[3][BN * 32];
  int tid = threadIdx.x, wv = tid >> 6, lane = tid & 63;
  int quad = lane >> 4, l15 = lane & 15;
  int bl = blockIdx.x + gridDim.x * blockIdx.y;
  int m0 = (bl % gridDim.y) * BM;
  int n0 = (bl / gridDim.y) * BN;
  int z = blockIdx.z;
  const ushort_t* A = p.A + (long)z * p.sA;
  const ushort_t* Bm = p.Bm + (long)z * p.sB;
  int wm = (wv & 1) * (BM / 2), wn = (wv >> 1) * (BN / 2);
  f32x4 acc[TI][TJ];
#pragma unroll
  for (int i = 0; i < TI; i++)
#pragma unroll
    for (int j = 0; j < TJ; j++)
#pragma unroll
      for (int r = 0; r < 4; r++) acc[i][j][r] = 0.f;

  int srow = tid >> 2;
  int sc = ((tid & 3) ^ ((tid >> 3) & 3)) * 8;
  const ushort_t* ga = A + (long)(m0 + srow) * p.lda + sc;
  const ushort_t* gb = Bm + (long)(n0 + srow) * p.ldb + sc;
  long a64 = (long)64 * p.lda, b64 = (long)64 * p.ldb;
  int aswz = (quad ^ ((l15 >> 1) & 3)) * 8;
  int nsteps = p.K >> 5;

  // prologue: stage tiles 0 and 1 (K >= 64 always here)
#pragma unroll
  for (int rr = 0; rr < RA; rr++) gl_lds16(ga + rr * a64, As[0] + rr * 2048 + wv * 512);
#pragma unroll
  for (int rr = 0; rr < RB; rr++) gl_lds16(gb + rr * b64, Bs[0] + rr * 2048 + wv * 512);
#pragma unroll
  for (int rr = 0; rr < RA; rr++) gl_lds16(ga + 32 + rr * a64, As[1] + rr * 2048 + wv * 512);
#pragma unroll
  for (int rr = 0; rr < RB; rr++) gl_lds16(gb + 32 + rr * b64, Bs[1] + rr * 2048 + wv * 512);

  for (int ks = 0; ks < nsteps; ks++) {
    int cur = ks % 3;
    // wait for tile ks only (leave tile ks+1 in flight), then raw barrier (no drain)
    if (ks + 1 < nsteps) __builtin_amdgcn_s_waitcnt(0xF70 | NV);
    else                 __builtin_amdgcn_s_waitcnt(0xF70);
    __builtin_amdgcn_s_barrier();
    if (ks + 2 < nsteps) {
      int nb = (ks + 2) % 3;
      const ushort_t* a0 = ga + (ks + 2) * 32;
      const ushort_t* b0 = gb + (ks + 2) * 32;
#pragma unroll
      for (int rr = 0; rr < RA; rr++) gl_lds16(a0 + rr * a64, As[nb] + rr * 2048 + wv * 512);
#pragma unroll
      for (int rr = 0; rr < RB; rr++) gl_lds16(b0 + rr * b64, Bs[nb] + rr * 2048 + wv * 512);
    }
    short8 av[TI], bv[TJ];
#pragma unroll
    for (int ti = 0; ti < TI; ti++)
      av[ti] = *(const short8*)&As[cur][(wm + ti * 16 + l15) * 32 + aswz];
#pragma unroll
    for (int tj = 0; tj < TJ; tj++)
      bv[tj] = *(const short8*)&Bs[cur][(wn + tj * 16 + l15) * 32 + aswz];
#pragma unroll
    for (int ti = 0; ti < TI; ti++)
#pragma unroll
      for (int tj = 0; tj < TJ; tj++)
        acc[ti][tj] = __builtin_amdgcn_mfma_f32_16x16x32_bf16(av[ti], bv[tj], acc[ti][tj], 0, 0, 0);
  }

  float g = 0.f;
  if constexpr (EPI == 2) g = 1.f / (1.f + expf(-p.gate[0]));
#pragma unroll
  for (int ti = 0; ti < TI; ti++) {
#pragma unroll
    for (int tj = 0; tj < TJ; tj++) {
#pragma unroll
      for (int r = 0; r < 4; r++) {
        int gm = m0 + wm + ti * 16 + quad * 4 + r;
        int n = n0 + wn + tj * 16 + l15;
        float v = acc[ti][tj][r];
        if constexpr (EPI == 0) {
          v += p.biasf[n];
          int bb = gm >> 10, tt = gm & 1023;
          if (n < 512) {
            int h = n >> 6, d = n & 63;
            // pre-scale q by 0.125*log2(e) so flash can use exp2 directly
            p.qp[((long)(bb * 8 + h) * 1024 + tt) * 64 + d] = f2b(v * 0.18033688011112042f);
          } else if (n < 1024) {
            int n2 = n - 512, h = n2 >> 6, d = n2 & 63;
            p.kp[((long)(bb * 8 + h) * 1024 + tt) * 64 + d] = f2b(v);
          } else {
            int n2 = n - 1024, h = n2 >> 6, d = n2 & 63;
            p.vp[((long)(bb * 8 + h) * 1024 + tt) * 64 + d] = f2b(v);
          }
        } else if constexpr (EPI == 1) {
          p.outb[(long)z * p.sC + (long)gm * p.ldc + n] = f2b(v);
        } else if constexpr (EPI == 2) {
          v += p.biasf[n];
          long idx = (long)gm * 512 + n;
          p.outb[idx] = f2b(p.residf[idx] + g * v + (1.f - g) * b2f(p.auxb[idx]));
        } else if constexpr (EPI == 3) {
          v += p.biasf[n];
          p.outb[(long)gm * p.ldc + n] = f2b(gelu_fast(v));
        } else {
          v += p.biasf[n];
          long idx = (long)gm * 512 + n;
          p.outf[idx] = v + b2f(p.auxb[idx]);
        }
      }
    }
  }
}

// ---------------- Flash attention v2: S^T form, packed P writes, Q in regs ----------------
__global__ __launch_bounds__(256) void flash_k(const ushort_t* __restrict__ q,
                                               const ushort_t* __restrict__ k,
                                               const ushort_t* __restrict__ vT,
                                               ushort_t* __restrict__ ctx) {
  int bl = blockIdx.x + gridDim.x * blockIdx.y;
  int bh = bl % 64;
  int q0 = (bl / 64) * 128;
  int tid = threadIdx.x, wv = tid >> 6, lane = tid & 63;
  int quad = lane >> 4, l15 = lane & 15;
  __shared__ ushort_t Ks[2][64 * 64], Vt[2][64 * 64];
  __shared__ ushort_t Pt[128 * 64];
  int wm = wv * 32;

  short8 qf[2][2];
#pragma unroll
  for (int tq = 0; tq < 2; tq++)
#pragma unroll
    for (int kk = 0; kk < 2; kk++)
      qf[tq][kk] = *(const short8*)&q[((long)bh * 1024 + q0 + wm + tq * 16 + l15) * 64 + kk * 32 + quad * 8];

  int srow = tid >> 3;
  int sc = ((tid & 7) ^ ((tid >> 3) & 7)) * 8;
#pragma unroll
  for (int e = 0; e < 2; e++) {
    gl_lds16(&k[((long)bh * 1024 + e * 32 + srow) * 64 + sc], Ks[0] + e * 2048 + wv * 512);
    gl_lds16(&vT[((long)bh * 64 + e * 32 + srow) * 1024 + sc], Vt[0] + e * 2048 + wv * 512);
  }
  __syncthreads();

  f32x4 O[2][4];
#pragma unroll
  for (int tq = 0; tq < 2; tq++)
#pragma unroll
    for (int td = 0; td < 4; td++)
#pragma unroll
      for (int r = 0; r < 4; r++) O[tq][td][r] = 0.f;
  float ls[2] = {0.f, 0.f};

  int pswz = (l15 & 7) << 1;
  for (int kt = 0; kt < 16; kt++) {
    int cur = kt & 1;
    if (kt + 1 < 16) {
#pragma unroll
      for (int e = 0; e < 2; e++) {
        gl_lds16(&k[((long)bh * 1024 + (kt + 1) * 64 + e * 32 + srow) * 64 + sc], Ks[cur ^ 1] + e * 2048 + wv * 512);
        gl_lds16(&vT[((long)bh * 64 + e * 32 + srow) * 1024 + (kt + 1) * 64 + sc], Vt[cur ^ 1] + e * 2048 + wv * 512);
      }
    }
#pragma unroll
    for (int tq = 0; tq < 2; tq++) {
      f32x4 S[4];
#pragma unroll
      for (int tk = 0; tk < 4; tk++) {
#pragma unroll
        for (int r = 0; r < 4; r++) S[tk][r] = 0.f;
#pragma unroll
        for (int kk = 0; kk < 2; kk++) {
          short8 kf = *(const short8*)&Ks[cur][(tk * 16 + l15) * 64 + ((kk * 4 + quad) ^ (l15 & 7)) * 8];
          S[tk] = __builtin_amdgcn_mfma_f32_16x16x32_bf16(kf, qf[tq][kk], S[tk], 0, 0, 0);
        }
      }
#pragma unroll
      for (int tk = 0; tk < 4; tk++) {
        float p0 = exp2f(S[tk][0]);
        float p1 = exp2f(S[tk][1]);
        float p2 = exp2f(S[tk][2]);
        float p3 = exp2f(S[tk][3]);
        ls[tq] += (p0 + p1) + (p2 + p3);
        unsigned lo = __builtin_amdgcn_perm(__float_as_uint(p1), __float_as_uint(p0), 0x07060302u);
        unsigned hi = __builtin_amdgcn_perm(__float_as_uint(p3), __float_as_uint(p2), 0x07060302u);
        int gnum = (tk * 4 + quad) ^ pswz;
        uint2 pr; pr.x = lo; pr.y = hi;
        *(uint2*)&Pt[(wm + tq * 16 + l15) * 64 + gnum * 4] = pr;
      }
    }
#pragma unroll
    for (int tq = 0; tq < 2; tq++) {
#pragma unroll
      for (int kk = 0; kk < 2; kk++) {
        short8 pf = *(const short8*)&Pt[(wm + tq * 16 + l15) * 64 + (((kk * 8 + quad * 2) ^ pswz)) * 4];
#pragma unroll
        for (int td = 0; td < 4; td++) {
          short8 vf = *(const short8*)&Vt[cur][(td * 16 + l15) * 64 + ((kk * 4 + quad) ^ (l15 & 7)) * 8];
          O[tq][td] = __builtin_amdgcn_mfma_f32_16x16x32_bf16(pf, vf, O[tq][td], 0, 0, 0);
        }
      }
    }
    __syncthreads();
  }
#pragma unroll
  for (int tq = 0; tq < 2; tq++) {
    ls[tq] += __shfl_xor(ls[tq], 16);
    ls[tq] += __shfl_xor(ls[tq], 32);
  }
  int bb = bh >> 3, h = bh & 7;
#pragma unroll
  for (int tq = 0; tq < 2; tq++) {
#pragma unroll
    for (int r = 0; r < 4; r++) {
      int qrow = quad * 4 + r;
      float inv = 1.f / __shfl(ls[tq], (lane & 48) | qrow);
      long row = (long)bb * 1024 + q0 + wm + tq * 16 + qrow;
#pragma unroll
      for (int td = 0; td < 4; td++)
        ctx[row * 512 + h * 64 + td * 16 + l15] = f2b(O[tq][td][r] * inv);
    }
  }
}

// ---------------- launch ----------------
extern "C" void kernel_launch(void* const* d_in, const int* in_sizes, int n_in,
                              void* d_out, int out_size, void* d_ws, size_t ws_size,
                              hipStream_t stream) {
  const float* x    = (const float*)d_in[0];
  const int* posv   = (const int*)d_in[1];
  const int* posh   = (const int*)d_in[2];
  const float* n1w  = (const float*)d_in[3];
  const float* n1b  = (const float*)d_in[4];
  const float* in_w = (const float*)d_in[5];
  const float* in_b = (const float*)d_in[6];
  const float* outw = (const float*)d_in[7];
  const float* outb = (const float*)d_in[8];
  const float* n2w  = (const float*)d_in[9];
  const float* n2b  = (const float*)d_in[10];
  const float* w1   = (const float*)d_in[11];
  const float* b1   = (const float*)d_in[12];
  const float* w2   = (const float*)d_in[13];
  const float* b2   = (const float*)d_in[14];
  const float* gate = (const float*)d_in[15];
  float* out = (float*)d_out;

  char* ws = (char*)d_ws;
  const size_t MB = 1024 * 1024;
  ushort_t* q    = (ushort_t*)(ws + 0 * MB);
  ushort_t* kk   = (ushort_t*)(ws + 8 * MB);
  ushort_t* vtmp = (ushort_t*)(ws + 16 * MB);
  ushort_t* vT   = (ushort_t*)(ws + 24 * MB);
  ushort_t* kw   = (ushort_t*)(ws + 32 * MB);
  ushort_t* xn   = (ushort_t*)(ws + 48 * MB);
  ushort_t* xnT  = (ushort_t*)(ws + 56 * MB);
  ushort_t* ctx  = (ushort_t*)(ws + 64 * MB);
  ushort_t* ko   = (ushort_t*)(ws + 72 * MB);
  ushort_t* x1b  = (ushort_t*)(ws + 80 * MB);
  ushort_t* xn2  = (ushort_t*)(ws + 16 * MB);   // overlay vtmp
  ushort_t* inwb = (ushort_t*)(ws + 96 * MB);
  ushort_t* owb  = (ushort_t*)(ws + 98 * MB);
  ushort_t* w1b  = (ushort_t*)(ws + 99 * MB);
  ushort_t* w2b  = (ushort_t*)(ws + 101 * MB);
  ushort_t* h    = (ushort_t*)(ws + 24 * MB);   // 32 MB overlay (vT/kw/xn dead)

  cvt4_kernel<<<3072, 256, 0, stream>>>(in_w, outw, w1, w2, inwb, owb, w1b, w2b);
  ln_kernel<<<2048, 256, 0, stream>>>(x, n1w, n1b, xn);
  kw_kernel<<<8192, 256, 0, stream>>>(posv, posh, kw);
  // qkv: [8192,1536] = xn @ in_w^T
  {
    GemmP p = {};
    p.A = xn; p.Bm = inwb; p.lda = 512; p.ldb = 512; p.K = 512;
    p.biasf = in_b; p.qp = q; p.kp = kk; p.vp = vtmp;
    gemm_k<128, 128, 0><<<dim3(12, 64, 1), 256, 0, stream>>>(p);
  }
  tr_kernel<<<dim3(1, 16, 64), 256, 0, stream>>>(vtmp, vT, 1024, 64);
  flash_k<<<dim3(8, 64, 1), 256, 0, stream>>>(q, kk, vT, ctx);
  tr_kernel<<<dim3(8, 16, 8), 256, 0, stream>>>(xn, xnT, 1024, 512);
  // kernel_out = kw @ xn (batched) -> ko bf16
  {
    GemmP p = {};
    p.A = kw; p.Bm = xnT; p.lda = 1024; p.ldb = 1024; p.ldc = 512; p.K = 1024;
    p.sA = 1024L * 1024; p.sB = 512L * 1024; p.sC = 1024L * 512;
    p.outb = ko;
    gemm_k<64, 128, 1><<<dim3(4, 16, 8), 256, 0, stream>>>(p);
  }
  // std_out + gate combine -> x1 bf16
  {
    GemmP p = {};
    p.A = ctx; p.Bm = owb; p.lda = 512; p.ldb = 512; p.K = 512;
    p.biasf = outb; p.residf = x; p.auxb = ko; p.outb = x1b; p.gate = gate;
    gemm_k<64, 64, 2><<<dim3(8, 128, 1), 256, 0, stream>>>(p);
  }
  ln_b_kernel<<<2048, 256, 0, stream>>>(x1b, n2w, n2b, xn2);
  // MLP1 + GELU -> h bf16
  {
    GemmP p = {};
    p.A = xn2; p.Bm = w1b; p.lda = 512; p.ldb = 512; p.ldc = 2048; p.K = 512;
    p.biasf = b1; p.outb = h;
    gemm_k<128, 128, 3><<<dim3(16, 64, 1), 256, 0, stream>>>(p);
  }
  // MLP2 + residual(x1b) -> out f32
  {
    GemmP p = {};
    p.A = h; p.Bm = w2b; p.lda = 2048; p.ldb = 2048; p.K = 2048;
    p.biasf = b2; p.auxb = x1b; p.outf = out;
    gemm_k<64, 128, 4><<<dim3(4, 128, 1), 256, 0, stream>>>(p);
  }
}